// Round 1
// baseline (1492.513 us; speedup 1.0000x reference)
//
#include <hip/hip_runtime.h>

// Shapes
#define BATCH 8
#define CH    512
#define HDS   8
#define HD    64        // head_dim = 512/8
#define HW    1024      // 32*32 pooled tokens
#define IMG   50176     // 224*224
#define NPB   524288    // CH*HW per batch
#define EPSV  1e-5f

// ---------------------------------------------------------------------------
// K1: 7x7 avgpool, one block per (b,c). Coalesced 224-float row reads,
// LDS column sums, 32 threads produce the 32 pooled outputs per row.
// Fused: per-(b,c) sum/sumsq of pooled values for GroupNorm stats.
// ---------------------------------------------------------------------------
__global__ __launch_bounds__(256) void k_pool(const float* __restrict__ x,
                                              float* __restrict__ y,
                                              float* __restrict__ part) {
    int bc = blockIdx.x;                      // b*512 + c
    const float* xp = x + (size_t)bc * IMG;
    float* yp = y + (size_t)bc * HW;
    __shared__ float ls[224];
    int t = threadIdx.x;
    float bsum = 0.f, bsq = 0.f;

    for (int hq = 0; hq < 32; ++hq) {
        const float* row = xp + hq * 7 * 224;
        float s = 0.f;
        if (t < 224) {
            #pragma unroll
            for (int r = 0; r < 7; ++r) s += row[r * 224 + t];
        }
        __syncthreads();                      // protect ls reads of prev iter
        if (t < 224) ls[t] = s;
        __syncthreads();
        if (t < 32) {
            float a = 0.f;
            #pragma unroll
            for (int j = 0; j < 7; ++j) a += ls[t * 7 + j];  // 7t%32 distinct: no conflict
            a *= (1.f / 49.f);
            yp[hq * 32 + t] = a;
            bsum += a; bsq += a * a;
        }
    }
    // wave-0 reduce (lanes 32..63 hold zeros)
    if (t < 64) {
        #pragma unroll
        for (int o = 32; o > 0; o >>= 1) {
            bsum += __shfl_down(bsum, o);
            bsq  += __shfl_down(bsq, o);
        }
        if (t == 0) { part[bc * 2] = bsum; part[bc * 2 + 1] = bsq; }
    }
}

// ---------------------------------------------------------------------------
// K2: finalize GroupNorm stats per batch: mu and rsqrt(var+eps)
// ---------------------------------------------------------------------------
__global__ __launch_bounds__(256) void k_stats(const float* __restrict__ part,
                                               float* __restrict__ stats) {
    int b = blockIdx.x;
    int t = threadIdx.x;
    float s = 0.f, q = 0.f;
    #pragma unroll
    for (int i = 0; i < 2; ++i) {
        int idx = b * CH + t + i * 256;
        s += part[idx * 2];
        q += part[idx * 2 + 1];
    }
    #pragma unroll
    for (int o = 32; o > 0; o >>= 1) { s += __shfl_down(s, o); q += __shfl_down(q, o); }
    __shared__ float red[8];
    int w = t >> 6, ln = t & 63;
    if (ln == 0) { red[w * 2] = s; red[w * 2 + 1] = q; }
    __syncthreads();
    if (t == 0) {
        float S = 0.f, Q = 0.f;
        #pragma unroll
        for (int i = 0; i < 4; ++i) { S += red[i * 2]; Q += red[i * 2 + 1]; }
        float mu  = S / (float)NPB;
        float var = Q / (float)NPB - mu * mu;
        stats[b * 2]     = mu;
        stats[b * 2 + 1] = rsqrtf(var + EPSV);
    }
}

// ---------------------------------------------------------------------------
// K3: partial gram matrix of yn per (b, head), n-sliced 8 ways.
// LDS tile stored transposed [n][ch] with stride 68:
//   - b128 stores: lane-stride 68 floats -> 8 bank-quads x 8 lanes = 8 phases (free)
//   - compute reads tile[kk][d0:4]/tile[kk][e0:4]: broadcast + <=2-way (free)
// Also emits per-channel yn sums (for v_mean).
// ---------------------------------------------------------------------------
#define SC 68
__global__ __launch_bounds__(256) void k_gram(const float* __restrict__ y,
                                              const float* __restrict__ gamma,
                                              const float* __restrict__ beta,
                                              const float* __restrict__ stats,
                                              float* __restrict__ Gpart,
                                              float* __restrict__ ysum) {
    int blk = blockIdx.x;          // 0..511
    int bh  = blk >> 3;            // (b,h)
    int sl  = blk & 7;             // n-slice
    int b   = bh >> 3;
    int h   = bh & 7;
    __shared__ float tile[128 * SC];
    int t = threadIdx.x;
    float mu = stats[b * 2], rs = stats[b * 2 + 1];

    int nt = t & 63, cb = t >> 6;
    int n0 = sl * 128;
    #pragma unroll
    for (int p = 0; p < 8; ++p) {
        int nn  = (p & 1) * 64 + nt;
        int ch0 = ((p >> 1) * 4 + cb) * 4;
        int c0  = h * HD + ch0;
        const float* src = y + ((size_t)(b * CH + c0)) * HW + n0 + nn;
        float4 w;
        w.x = (src[0]      - mu) * rs * gamma[c0 + 0] + beta[c0 + 0];
        w.y = (src[HW]     - mu) * rs * gamma[c0 + 1] + beta[c0 + 1];
        w.z = (src[2 * HW] - mu) * rs * gamma[c0 + 2] + beta[c0 + 2];
        w.w = (src[3 * HW] - mu) * rs * gamma[c0 + 3] + beta[c0 + 3];
        *(float4*)&tile[nn * SC + ch0] = w;
    }
    __syncthreads();

    if (t < 64) {   // per-channel yn sums for this slice
        float s = 0.f;
        for (int kk = 0; kk < 128; ++kk) s += tile[kk * SC + t];
        ysum[blk * 64 + t] = s;
    }

    int tx = t & 15, ty = t >> 4;
    int d0 = ty * 4, e0 = tx * 4;
    float acc[4][4];
    #pragma unroll
    for (int i = 0; i < 4; ++i)
        #pragma unroll
        for (int j = 0; j < 4; ++j) acc[i][j] = 0.f;

    #pragma unroll 4
    for (int kk = 0; kk < 128; ++kk) {
        float4 a  = *(const float4*)&tile[kk * SC + d0];
        float4 bb = *(const float4*)&tile[kk * SC + e0];
        float av[4] = {a.x, a.y, a.z, a.w};
        float bv[4] = {bb.x, bb.y, bb.z, bb.w};
        #pragma unroll
        for (int i = 0; i < 4; ++i)
            #pragma unroll
            for (int j = 0; j < 4; ++j) acc[i][j] = fmaf(av[i], bv[j], acc[i][j]);
    }
    float* gp = Gpart + (size_t)blk * 4096;
    #pragma unroll
    for (int i = 0; i < 4; ++i)
        #pragma unroll
        for (int j = 0; j < 4; ++j)
            gp[(d0 + i) * 64 + (e0 + j)] = acc[i][j];
}

// ---------------------------------------------------------------------------
// K4: combine gram partials, softmax over e with qk scaling, dot with v_mean,
// sigmoid -> gate[b*512+c]
// ---------------------------------------------------------------------------
__global__ __launch_bounds__(256) void k_attn(const float* __restrict__ Gpart,
                                              const float* __restrict__ ysum,
                                              const float* __restrict__ wq,
                                              const float* __restrict__ wk,
                                              const float* __restrict__ wv,
                                              float* __restrict__ gate) {
    int bh = blockIdx.x;           // 0..63
    int h  = bh & 7;
    int t  = threadIdx.x;
    __shared__ float G[64 * 65];   // +1 pad: row reads conflict-free
    __shared__ float vm[64];
    __shared__ float wkl[64];

    #pragma unroll
    for (int i = 0; i < 16; ++i) {
        int idx = t + 256 * i;
        float s = 0.f;
        #pragma unroll
        for (int p = 0; p < 8; ++p) s += Gpart[(size_t)(bh * 8 + p) * 4096 + idx];
        int d = idx >> 6, e = idx & 63;
        G[d * 65 + e] = s;
    }
    if (t < 64) {
        float s = 0.f;
        #pragma unroll
        for (int p = 0; p < 8; ++p) s += ysum[(bh * 8 + p) * 64 + t];
        int c = h * HD + t;
        vm[t]  = wv[c] * s * (1.f / 1024.f);   // v_mean[e]
        wkl[t] = wk[c];
    }
    __syncthreads();

    if (t < 64) {
        int c = h * HD + t;
        float qs = wq[c] * 0.125f;             // scale = 64^-0.5
        float m = -1e30f;
        for (int e = 0; e < 64; ++e) {
            float sv = qs * wkl[e] * G[t * 65 + e];
            m = fmaxf(m, sv);
        }
        float es = 0.f, dot = 0.f;
        for (int e = 0; e < 64; ++e) {
            float sv = qs * wkl[e] * G[t * 65 + e];
            float ex = __expf(sv - m);
            es += ex;
            dot += ex * vm[e];
        }
        float o = dot / es;
        gate[bh * 64 + t] = 1.f / (1.f + __expf(-o));
    }
}

// ---------------------------------------------------------------------------
// K5: out = gate[b,c] * x, float4 streaming
// ---------------------------------------------------------------------------
__global__ __launch_bounds__(256) void k_mul(const float* __restrict__ x,
                                             const float* __restrict__ gate,
                                             float* __restrict__ out) {
    int bc = blockIdx.x;
    float g = gate[bc];
    const float4* xp = (const float4*)(x + (size_t)bc * IMG);
    float4* op = (float4*)(out + (size_t)bc * IMG);
    for (int i = threadIdx.x; i < IMG / 4; i += 256) {
        float4 v = xp[i];
        v.x *= g; v.y *= g; v.z *= g; v.w *= g;
        op[i] = v;
    }
}

extern "C" void kernel_launch(void* const* d_in, const int* in_sizes, int n_in,
                              void* d_out, int out_size, void* d_ws, size_t ws_size,
                              hipStream_t stream) {
    const float* x     = (const float*)d_in[0];
    const float* gamma = (const float*)d_in[1];
    const float* beta  = (const float*)d_in[2];
    const float* wq    = (const float*)d_in[3];
    const float* wk    = (const float*)d_in[4];
    const float* wv    = (const float*)d_in[5];
    float* out = (float*)d_out;

    // workspace layout (floats); total ~25.4 MB
    float* ws    = (float*)d_ws;
    float* y     = ws;                 // 4,194,304  pooled tensor [8][512][1024]
    float* Gpart = ws + 4194304;       // 2,097,152  gram partials [512][4096]
    float* ysum  = ws + 6291456;       //    32,768  yn channel-sum partials [512][64]
    float* part  = ws + 6324224;       //     8,192  per-(b,c) sum/sumsq pairs
    float* stats = ws + 6332416;       //        16  (mu, rsqrt(var+eps)) per batch
    float* gate  = ws + 6332432;       //     4,096  sigmoid gates

    k_pool <<<BATCH * CH, 256, 0, stream>>>(x, y, part);
    k_stats<<<BATCH,      256, 0, stream>>>(part, stats);
    k_gram <<<512,        256, 0, stream>>>(y, gamma, beta, stats, Gpart, ysum);
    k_attn <<<64,         256, 0, stream>>>(Gpart, ysum, wq, wk, wv, gate);
    k_mul  <<<BATCH * CH, 256, 0, stream>>>(x, gate, out);
}